// Round 8
// baseline (32.967 us; speedup 1.0000x reference)
//
#include <hip/hip_runtime.h>

#define DEV __device__ __forceinline__

typedef unsigned u32;
typedef u32 u32x2 __attribute__((ext_vector_type(2)));

// ---------- DPP helpers (ctrl/masks must be ICEs -> template params) ----------

template<int CTRL>
DEV int dpp_full(int src) {
    return __builtin_amdgcn_update_dpp(src, src, CTRL, 0xF, 0xF, false);
}
template<int CTRL, int RM, int BM>
DEV int dpp_masked(int old, int src) {
    return __builtin_amdgcn_update_dpp(old, src, CTRL, RM, BM, false);
}

// ---------- cross-lane xor-shuffle: ZERO DS ops ----------
// xor1 = quad_perm[1,0,3,2] (0xB1); xor2 = quad_perm[2,3,0,1] (0x4E);
// xor4 = xor3 (quad_perm[3,2,1,0]=0x1B) then xor7 (row_half_mirror=0x141);
// xor8 = row_ror:8 (0x128); xor16 = permlane16_swap; xor32 = permlane32_swap.

template<int B>
DEV float lshfl(float x, bool p32, bool p16) {
    int xi = __float_as_int(x);
    if constexpr (B == 0) {
        return __int_as_float(dpp_full<0xB1>(xi));
    } else if constexpr (B == 1) {
        return __int_as_float(dpp_full<0x4E>(xi));
    } else if constexpr (B == 2) {
        return __int_as_float(dpp_full<0x141>(dpp_full<0x1B>(xi)));
    } else if constexpr (B == 3) {
        return __int_as_float(dpp_full<0x128>(xi));
    } else if constexpr (B == 4) {
#if __has_builtin(__builtin_amdgcn_permlane16_swap)
        u32x2 r = __builtin_amdgcn_permlane16_swap((u32)xi, (u32)xi, false, false);
        return __int_as_float((int)(p16 ? r.x : r.y));
#else
        return __int_as_float(__builtin_amdgcn_ds_swizzle(xi, 0x401F));
#endif
    } else {
        u32x2 r = __builtin_amdgcn_permlane32_swap((u32)xi, (u32)xi, false, false);
        return __int_as_float((int)(p32 ? r.x : r.y));
    }
}

// Convention-independent probes: which pair element holds the OTHER group's value.
DEV bool probe32(int lane) {
    u32 p = (u32)((lane >> 5) & 1);
    u32x2 r = __builtin_amdgcn_permlane32_swap(p, p, false, false);
    return r.x == (p ^ 1u);
}
DEV bool probe16(int lane) {
#if __has_builtin(__builtin_amdgcn_permlane16_swap)
    u32 p = (u32)((lane >> 4) & 1);
    u32x2 r = __builtin_amdgcn_permlane16_swap(p, p, false, false);
    return r.x == (p ^ 1u);
#else
    return false;
#endif
}

// ---------- complex pair primitives (fp32) ----------

DEV void rx_pair(float& r0, float& i0, float& r1, float& i1, float c, float s) {
    float nr0 = fmaf(c, r0,  s * i1);
    float ni0 = fmaf(c, i0, -s * r1);
    float nr1 = fmaf(c, r1,  s * i0);
    float ni1 = fmaf(c, i1, -s * r0);
    r0 = nr0; i0 = ni0; r1 = nr1; i1 = ni1;
}

DEV void ry_pair(float& r0, float& i0, float& r1, float& i1, float c, float s) {
    float nr0 = fmaf(c, r0, -s * r1);
    float ni0 = fmaf(c, i0, -s * i1);
    float nr1 = fmaf(c, r1,  s * r0);
    float ni1 = fmaf(c, i1,  s * i0);
    r0 = nr0; i0 = ni0; r1 = nr1; i1 = ni1;
}

DEV void rz_amp(float& r, float& i, float c, float ss) {
    float nr = fmaf(c, r, -ss * i);
    float ni = fmaf(c, i,  ss * r);
    r = nr; i = ni;
}

// ---------- gates on flat-index bit B (B = 7 - qubit) ----------
// layout: amp idx = k*64 + lane; bits 0..5 = lane bits, 6 = k bit0, 7 = k bit1

template<int B>
DEV void apply_rx(float (&re)[4], float (&im)[4], int lane, bool p32, bool p16,
                  float c, float s) {
    if constexpr (B == 7) {
        rx_pair(re[0], im[0], re[2], im[2], c, s);
        rx_pair(re[1], im[1], re[3], im[3], c, s);
    } else if constexpr (B == 6) {
        rx_pair(re[0], im[0], re[1], im[1], c, s);
        rx_pair(re[2], im[2], re[3], im[3], c, s);
    } else {
#pragma unroll
        for (int k = 0; k < 4; ++k) {
            float pr = lshfl<B>(re[k], p32, p16);
            float pi = lshfl<B>(im[k], p32, p16);
            re[k] = fmaf(c, re[k],  s * pi);   // RX symmetric: no hi/lo branch
            im[k] = fmaf(c, im[k], -s * pr);
        }
    }
}

template<int B>
DEV void apply_ry(float (&re)[4], float (&im)[4], int lane, bool p32, bool p16,
                  float c, float s) {
    if constexpr (B == 7) {
        ry_pair(re[0], im[0], re[2], im[2], c, s);
        ry_pair(re[1], im[1], re[3], im[3], c, s);
    } else if constexpr (B == 6) {
        ry_pair(re[0], im[0], re[1], im[1], c, s);
        ry_pair(re[2], im[2], re[3], im[3], c, s);
    } else {
        float ssel = ((lane >> B) & 1) ? s : -s;
#pragma unroll
        for (int k = 0; k < 4; ++k) {
            float pr = lshfl<B>(re[k], p32, p16);
            float pi = lshfl<B>(im[k], p32, p16);
            re[k] = fmaf(c, re[k], ssel * pr);
            im[k] = fmaf(c, im[k], ssel * pi);
        }
    }
}

template<int B>
DEV void apply_rz(float (&re)[4], float (&im)[4], int lane, float c, float s) {
    if constexpr (B == 7) {
        rz_amp(re[0], im[0], c, -s); rz_amp(re[1], im[1], c, -s);
        rz_amp(re[2], im[2], c,  s); rz_amp(re[3], im[3], c,  s);
    } else if constexpr (B == 6) {
        rz_amp(re[0], im[0], c, -s); rz_amp(re[1], im[1], c,  s);
        rz_amp(re[2], im[2], c, -s); rz_amp(re[3], im[3], c,  s);
    } else {
        float ss = ((lane >> B) & 1) ? s : -s;
#pragma unroll
        for (int k = 0; k < 4; ++k) rz_amp(re[k], im[k], c, ss);
    }
}

// CNOT(ctrl=BC, tgt=BT): masked DPP where possible (1 instr per value).
template<int BC, int BT>
DEV void apply_cnot(float (&re)[4], float (&im)[4], int lane, bool p32, bool p16) {
    if constexpr (BC == 7 && BT == 6) {
        float tr = re[2], ti = im[2];
        re[2] = re[3]; im[2] = im[3];
        re[3] = tr;    im[3] = ti;
    } else if constexpr (BC == 6) {
        // ctrl = k bit0 (k=1,3 always on): unconditional xor32 swap
        re[1] = lshfl<5>(re[1], p32, p16); im[1] = lshfl<5>(im[1], p32, p16);
        re[3] = lshfl<5>(re[3], p32, p16); im[3] = lshfl<5>(im[3], p32, p16);
    } else if constexpr (BC == 5 && BT == 4) {
        // ctrl = lane bit5: xor16 partner (permlane16, VALU) + cndmask
        bool ctrl = (lane >> 5) & 1;
#pragma unroll
        for (int k = 0; k < 4; ++k) {
            float pr = lshfl<4>(re[k], p32, p16);
            float pi = lshfl<4>(im[k], p32, p16);
            re[k] = ctrl ? pr : re[k];
            im[k] = ctrl ? pi : im[k];
        }
    } else if constexpr (BC == 4 && BT == 3) {
        // ctrl = lane bit4 -> rows 1,3 (row_mask 0xA); xor8 = row_ror:8
#pragma unroll
        for (int k = 0; k < 4; ++k) {
            int r = __float_as_int(re[k]), i = __float_as_int(im[k]);
            re[k] = __int_as_float(dpp_masked<0x128, 0xA, 0xF>(r, r));
            im[k] = __int_as_float(dpp_masked<0x128, 0xA, 0xF>(i, i));
        }
    } else if constexpr (BC == 3 && BT == 2) {
        // ctrl = lane bit3 -> banks 2,3 (bank_mask 0xC); xor4 = xor3 then xor7
#pragma unroll
        for (int k = 0; k < 4; ++k) {
            int r = __float_as_int(re[k]), i = __float_as_int(im[k]);
            int tr = dpp_full<0x1B>(r), ti = dpp_full<0x1B>(i);
            re[k] = __int_as_float(dpp_masked<0x141, 0xF, 0xC>(r, tr));
            im[k] = __int_as_float(dpp_masked<0x141, 0xF, 0xC>(i, ti));
        }
    } else if constexpr (BC == 2 && BT == 1) {
        // ctrl = lane bit2 -> banks 1,3 (bank_mask 0xA); xor2 = quad_perm 0x4E
#pragma unroll
        for (int k = 0; k < 4; ++k) {
            int r = __float_as_int(re[k]), i = __float_as_int(im[k]);
            re[k] = __int_as_float(dpp_masked<0x4E, 0xF, 0xA>(r, r));
            im[k] = __int_as_float(dpp_masked<0x4E, 0xF, 0xA>(i, i));
        }
    } else {
        // BC==1, BT==0: quad_perm [0,1,3,2] = 0xB4
#pragma unroll
        for (int k = 0; k < 4; ++k) {
            re[k] = __int_as_float(dpp_full<0xB4>(__float_as_int(re[k])));
            im[k] = __int_as_float(dpp_full<0xB4>(__float_as_int(im[k])));
        }
    }
}

// ---------- prep: cos/sin of 48 shared params into ws ----------

__global__ void qa_prep(const float* __restrict__ params, float* __restrict__ gc, int n) {
    int t = blockIdx.x * blockDim.x + threadIdx.x;
    if (t < n) {
        float th = params[t] * 0.5f;
        gc[2 * t]     = cosf(th);
        gc[2 * t + 1] = sinf(th);
    }
}

// ---------- main: one wave per batch element ----------

__global__ __launch_bounds__(256, 8) void qa_sim(
    const float* __restrict__ x, const float* __restrict__ gc,
    float* __restrict__ out, int batch)
{
    int tid  = blockIdx.x * 256 + threadIdx.x;
    int b    = tid >> 6;
    int lane = threadIdx.x & 63;
    if (b >= batch) return;

    bool p32 = probe32(lane);
    bool p16 = probe16(lane);

    // ---- bulk-hoist all 96 shared cos/sin values (uniform -> wide s_loads) ----
    float g[96];
#pragma unroll
    for (int i = 0; i < 96; ++i) g[i] = gc[i];

    // ---- direct product-state encoding ----
    // RX(x_i)^{(i)} |0..0>  =>  amp(idx) = (prod mag) * (-i)^popcount(idx),
    // mag factor for qubit i = bit(7-i)(idx) ? sin(x_i/2) : cos(x_i/2).
    const float* xb = x + b * 8;
    float4 xlo = *(const float4*)xb;
    float4 xhi = *(const float4*)(xb + 4);
    float c_[8], s_[8];
    __sincosf(xlo.x * 0.5f, &s_[0], &c_[0]);
    __sincosf(xlo.y * 0.5f, &s_[1], &c_[1]);
    __sincosf(xlo.z * 0.5f, &s_[2], &c_[2]);
    __sincosf(xlo.w * 0.5f, &s_[3], &c_[3]);
    __sincosf(xhi.x * 0.5f, &s_[4], &c_[4]);
    __sincosf(xhi.y * 0.5f, &s_[5], &c_[5]);
    __sincosf(xhi.z * 0.5f, &s_[6], &c_[6]);
    __sincosf(xhi.w * 0.5f, &s_[7], &c_[7]);

    // qubits 2..7 live on lane bits 5..0
    float m6;
    m6  = ((lane >> 5) & 1) ? s_[2] : c_[2];
    m6 *= ((lane >> 4) & 1) ? s_[3] : c_[3];
    m6 *= ((lane >> 3) & 1) ? s_[4] : c_[4];
    m6 *= ((lane >> 2) & 1) ? s_[5] : c_[5];
    m6 *= ((lane >> 1) & 1) ? s_[6] : c_[6];
    m6 *= ( lane       & 1) ? s_[7] : c_[7];
    // k bit0 = flat bit6 = qubit1; k bit1 = flat bit7 = qubit0
    float kf[4] = { c_[0] * c_[1], c_[0] * s_[1], s_[0] * c_[1], s_[0] * s_[1] };
    const int kpc[4] = { 0, 1, 1, 2 };
    int pcl = __popc((u32)lane);

    float re[4], im[4];
#pragma unroll
    for (int k = 0; k < 4; ++k) {
        float mk = m6 * kf[k];
        int p = pcl + kpc[k];
        float sgn = (p & 2) ? -mk : mk;   // (-i)^p real part sign when even
        re[k] = (p & 1) ? 0.f : sgn;
        im[k] = (p & 1) ? -sgn : 0.f;
    }

    // ---- variational layers: g[2*j],g[2*j+1] = cos,sin of params[l][i][{RY,RZ,RX}] ----
#define VQ(l, i) { const int j = (l) * 24 + (i) * 3;                            \
                   apply_ry<7 - (i)>(re, im, lane, p32, p16, g[2*j],   g[2*j+1]); \
                   apply_rz<7 - (i)>(re, im, lane,           g[2*j+2], g[2*j+3]); }
#define CN(i)    apply_cnot<7 - (i), 6 - (i)>(re, im, lane, p32, p16);
#define RXQ(l,i) { const int j = (l) * 24 + (i) * 3 + 2;                        \
                   apply_rx<7 - (i)>(re, im, lane, p32, p16, g[2*j], g[2*j+1]); }
#define LAYER(l) \
    VQ(l,0) CN(0) VQ(l,1) CN(1) VQ(l,2) CN(2) VQ(l,3) CN(3) \
    VQ(l,4) CN(4) VQ(l,5) CN(5) VQ(l,6) CN(6) VQ(l,7)       \
    RXQ(l,0) RXQ(l,1) RXQ(l,2) RXQ(l,3) RXQ(l,4) RXQ(l,5) RXQ(l,6) RXQ(l,7)

    LAYER(0)
    LAYER(1)
#undef LAYER
#undef RXQ
#undef CN
#undef VQ

    // ---- <Z_i> readout ----
    float p0 = fmaf(re[0], re[0], im[0] * im[0]);
    float p1 = fmaf(re[1], re[1], im[1] * im[1]);
    float p2 = fmaf(re[2], re[2], im[2] * im[2]);
    float p3 = fmaf(re[3], re[3], im[3] * im[3]);

    float z0 = (p0 + p1) - (p2 + p3);   // qubit0 = bit7 = k bit1
    float z1 = (p0 - p1) + (p2 - p3);   // qubit1 = bit6 = k bit0
    float A  = (p0 + p1) + (p2 + p3);   // total prob per lane

    z0 += lshfl<0>(z0, p32, p16); z1 += lshfl<0>(z1, p32, p16);
    z0 += lshfl<1>(z0, p32, p16); z1 += lshfl<1>(z1, p32, p16);
    z0 += lshfl<2>(z0, p32, p16); z1 += lshfl<2>(z1, p32, p16);
    z0 += lshfl<3>(z0, p32, p16); z1 += lshfl<3>(z1, p32, p16);
    z0 += lshfl<4>(z0, p32, p16); z1 += lshfl<4>(z1, p32, p16);
    z0 += lshfl<5>(z0, p32, p16); z1 += lshfl<5>(z1, p32, p16);

    // pruned Walsh-Hadamard on A: D_b = signed sum over lane bit b
    float S = A, P, D0, D1, D2, D3, D4, D5;
    P = lshfl<0>(S, p32, p16); D0 = S - P; S += P;
    P = lshfl<1>(S, p32, p16); D1 = S - P; S += P;
    P = lshfl<2>(S, p32, p16); D2 = S - P; S += P;
    P = lshfl<3>(S, p32, p16); D3 = S - P; S += P;
    P = lshfl<4>(S, p32, p16); D4 = S - P; S += P;
    P = lshfl<5>(S, p32, p16); D5 = S - P;

    D0 += lshfl<1>(D0, p32, p16); D0 += lshfl<2>(D0, p32, p16);
    D0 += lshfl<3>(D0, p32, p16); D0 += lshfl<4>(D0, p32, p16); D0 += lshfl<5>(D0, p32, p16);
    D1 += lshfl<2>(D1, p32, p16); D1 += lshfl<3>(D1, p32, p16);
    D1 += lshfl<4>(D1, p32, p16); D1 += lshfl<5>(D1, p32, p16);
    D2 += lshfl<3>(D2, p32, p16); D2 += lshfl<4>(D2, p32, p16); D2 += lshfl<5>(D2, p32, p16);
    D3 += lshfl<4>(D3, p32, p16); D3 += lshfl<5>(D3, p32, p16);
    D4 += lshfl<5>(D4, p32, p16);

    if (lane == 0) {
        // qubit i (2..7) = lane bit 7-i -> D_{7-i}
        float4* o = (float4*)(out + b * 8);
        o[0] = make_float4(z0, z1, D5, D4);
        o[1] = make_float4(D3, D2, D1, D0);
    }
}

extern "C" void kernel_launch(void* const* d_in, const int* in_sizes, int n_in,
                              void* d_out, int out_size, void* d_ws, size_t ws_size,
                              hipStream_t stream) {
    const float* x      = (const float*)d_in[0];   // (BATCH, 8)
    const float* params = (const float*)d_in[1];   // (2, 8, 3) = 48
    float* out = (float*)d_out;
    float* gc  = (float*)d_ws;                     // 96 floats of (cos,sin)

    int batch   = in_sizes[0] / 8;
    int nparams = in_sizes[1];                     // 48

    qa_prep<<<1, 64, 0, stream>>>(params, gc, nparams);

    int blocks = (batch * 64 + 255) / 256;
    qa_sim<<<blocks, 256, 0, stream>>>(x, gc, out, batch);
}

// Round 9
// 29.224 us; speedup vs baseline: 1.1281x; 1.1281x over previous
//
#include <hip/hip_runtime.h>

#define DEV __device__ __forceinline__

typedef unsigned u32;
typedef u32 u32x2 __attribute__((ext_vector_type(2)));

// ---------- DPP helpers (ctrl/masks must be ICEs -> template params) ----------

template<int CTRL>
DEV int dpp_full(int src) {
    return __builtin_amdgcn_update_dpp(src, src, CTRL, 0xF, 0xF, false);
}
template<int CTRL, int RM, int BM>
DEV int dpp_masked(int old, int src) {
    return __builtin_amdgcn_update_dpp(old, src, CTRL, RM, BM, false);
}

// ---------- cross-lane xor-shuffle (champion r7 mix) ----------
// xor1/2/8 -> DPP (VALU); xor4/16 -> imm ds_swizzle (DS pipe, overlaps);
// xor32 -> permlane32_swap (VALU) + runtime-probed select.

template<int B>
DEV float lshfl(float x, bool px) {
    int xi = __float_as_int(x);
    if constexpr (B == 0) {
        return __int_as_float(dpp_full<0xB1>(xi));          // quad_perm [1,0,3,2]
    } else if constexpr (B == 1) {
        return __int_as_float(dpp_full<0x4E>(xi));          // quad_perm [2,3,0,1]
    } else if constexpr (B == 2) {
        return __int_as_float(__builtin_amdgcn_ds_swizzle(xi, 0x101F)); // xor4
    } else if constexpr (B == 3) {
        return __int_as_float(dpp_full<0x128>(xi));         // row_ror:8 = xor8
    } else if constexpr (B == 4) {
        return __int_as_float(__builtin_amdgcn_ds_swizzle(xi, 0x401F)); // xor16
    } else {
        u32x2 r = __builtin_amdgcn_permlane32_swap((u32)xi, (u32)xi, false, false);
        return __int_as_float((int)(px ? r.x : r.y));
    }
}

DEV bool probe32(int lane) {
    u32 p = (u32)((lane >> 5) & 1);
    u32x2 r = __builtin_amdgcn_permlane32_swap(p, p, false, false);
    return r.x == (p ^ 1u);
}

// ---------- complex pair primitives (fp32) ----------

DEV void rx_pair(float& r0, float& i0, float& r1, float& i1, float c, float s) {
    float nr0 = fmaf(c, r0,  s * i1);
    float ni0 = fmaf(c, i0, -s * r1);
    float nr1 = fmaf(c, r1,  s * i0);
    float ni1 = fmaf(c, i1, -s * r0);
    r0 = nr0; i0 = ni0; r1 = nr1; i1 = ni1;
}

DEV void ry_pair(float& r0, float& i0, float& r1, float& i1, float c, float s) {
    float nr0 = fmaf(c, r0, -s * r1);
    float ni0 = fmaf(c, i0, -s * i1);
    float nr1 = fmaf(c, r1,  s * r0);
    float ni1 = fmaf(c, i1,  s * i0);
    r0 = nr0; i0 = ni0; r1 = nr1; i1 = ni1;
}

DEV void rz_amp(float& r, float& i, float c, float ss) {
    float nr = fmaf(c, r, -ss * i);
    float ni = fmaf(c, i,  ss * r);
    r = nr; i = ni;
}

// ---------- gates on flat-index bit B (B = 7 - qubit), TWO elements/wave ----------
// state: k = e*4 + kk; amp idx(e) = kk*64 + lane; flat bit6 = kk bit0, bit7 = kk bit1.

template<int B>
DEV void apply_rx(float (&re)[8], float (&im)[8], int lane, bool px, float c, float s) {
    if constexpr (B == 7) {
        rx_pair(re[0], im[0], re[2], im[2], c, s); rx_pair(re[1], im[1], re[3], im[3], c, s);
        rx_pair(re[4], im[4], re[6], im[6], c, s); rx_pair(re[5], im[5], re[7], im[7], c, s);
    } else if constexpr (B == 6) {
        rx_pair(re[0], im[0], re[1], im[1], c, s); rx_pair(re[2], im[2], re[3], im[3], c, s);
        rx_pair(re[4], im[4], re[5], im[5], c, s); rx_pair(re[6], im[6], re[7], im[7], c, s);
    } else {
#pragma unroll
        for (int k = 0; k < 8; ++k) {
            float pr = lshfl<B>(re[k], px);
            float pi = lshfl<B>(im[k], px);
            re[k] = fmaf(c, re[k],  s * pi);   // RX symmetric: no hi/lo branch
            im[k] = fmaf(c, im[k], -s * pr);
        }
    }
}

template<int B>
DEV void apply_ry(float (&re)[8], float (&im)[8], int lane, bool px, float c, float s) {
    if constexpr (B == 7) {
        ry_pair(re[0], im[0], re[2], im[2], c, s); ry_pair(re[1], im[1], re[3], im[3], c, s);
        ry_pair(re[4], im[4], re[6], im[6], c, s); ry_pair(re[5], im[5], re[7], im[7], c, s);
    } else if constexpr (B == 6) {
        ry_pair(re[0], im[0], re[1], im[1], c, s); ry_pair(re[2], im[2], re[3], im[3], c, s);
        ry_pair(re[4], im[4], re[5], im[5], c, s); ry_pair(re[6], im[6], re[7], im[7], c, s);
    } else {
        float ssel = ((lane >> B) & 1) ? s : -s;
#pragma unroll
        for (int k = 0; k < 8; ++k) {
            float pr = lshfl<B>(re[k], px);
            float pi = lshfl<B>(im[k], px);
            re[k] = fmaf(c, re[k], ssel * pr);
            im[k] = fmaf(c, im[k], ssel * pi);
        }
    }
}

template<int B>
DEV void apply_rz(float (&re)[8], float (&im)[8], int lane, float c, float s) {
    if constexpr (B == 7) {
        // kk bit1: kk 0,1 -> -s ; kk 2,3 -> +s (per element)
        rz_amp(re[0], im[0], c, -s); rz_amp(re[1], im[1], c, -s);
        rz_amp(re[2], im[2], c,  s); rz_amp(re[3], im[3], c,  s);
        rz_amp(re[4], im[4], c, -s); rz_amp(re[5], im[5], c, -s);
        rz_amp(re[6], im[6], c,  s); rz_amp(re[7], im[7], c,  s);
    } else if constexpr (B == 6) {
        // kk bit0 parity
        rz_amp(re[0], im[0], c, -s); rz_amp(re[1], im[1], c,  s);
        rz_amp(re[2], im[2], c, -s); rz_amp(re[3], im[3], c,  s);
        rz_amp(re[4], im[4], c, -s); rz_amp(re[5], im[5], c,  s);
        rz_amp(re[6], im[6], c, -s); rz_amp(re[7], im[7], c,  s);
    } else {
        float ss = ((lane >> B) & 1) ? s : -s;
#pragma unroll
        for (int k = 0; k < 8; ++k) rz_amp(re[k], im[k], c, ss);
    }
}

// CNOT(ctrl=BC, tgt=BT): masked DPP where possible (champion r7 forms).
template<int BC, int BT>
DEV void apply_cnot(float (&re)[8], float (&im)[8], int lane, bool px) {
    if constexpr (BC == 7 && BT == 6) {
        // swap kk=2 <-> kk=3 within each element
        float tr, ti;
        tr = re[2]; ti = im[2]; re[2] = re[3]; im[2] = im[3]; re[3] = tr; im[3] = ti;
        tr = re[6]; ti = im[6]; re[6] = re[7]; im[6] = im[7]; re[7] = tr; im[7] = ti;
    } else if constexpr (BC == 6) {
        // ctrl = kk bit0 (kk=1,3 always on): unconditional xor32 swap
        re[1] = lshfl<5>(re[1], px); im[1] = lshfl<5>(im[1], px);
        re[3] = lshfl<5>(re[3], px); im[3] = lshfl<5>(im[3], px);
        re[5] = lshfl<5>(re[5], px); im[5] = lshfl<5>(im[5], px);
        re[7] = lshfl<5>(re[7], px); im[7] = lshfl<5>(im[7], px);
    } else if constexpr (BC == 5 && BT == 4) {
        bool ctrl = (lane >> 5) & 1;
#pragma unroll
        for (int k = 0; k < 8; ++k) {
            float pr = lshfl<4>(re[k], px);
            float pi = lshfl<4>(im[k], px);
            re[k] = ctrl ? pr : re[k];
            im[k] = ctrl ? pi : im[k];
        }
    } else if constexpr (BC == 4 && BT == 3) {
        // ctrl = lane bit4 -> rows 1,3 (row_mask 0xA); xor8 = row_ror:8
#pragma unroll
        for (int k = 0; k < 8; ++k) {
            int r = __float_as_int(re[k]), i = __float_as_int(im[k]);
            re[k] = __int_as_float(dpp_masked<0x128, 0xA, 0xF>(r, r));
            im[k] = __int_as_float(dpp_masked<0x128, 0xA, 0xF>(i, i));
        }
    } else if constexpr (BC == 3 && BT == 2) {
        // ctrl = lane bit3 -> banks 2,3 (bank_mask 0xC); xor4 = xor3 then xor7
#pragma unroll
        for (int k = 0; k < 8; ++k) {
            int r = __float_as_int(re[k]), i = __float_as_int(im[k]);
            int tr = dpp_full<0x1B>(r), ti = dpp_full<0x1B>(i);
            re[k] = __int_as_float(dpp_masked<0x141, 0xF, 0xC>(r, tr));
            im[k] = __int_as_float(dpp_masked<0x141, 0xF, 0xC>(i, ti));
        }
    } else if constexpr (BC == 2 && BT == 1) {
        // ctrl = lane bit2 -> banks 1,3 (bank_mask 0xA); xor2 = quad_perm 0x4E
#pragma unroll
        for (int k = 0; k < 8; ++k) {
            int r = __float_as_int(re[k]), i = __float_as_int(im[k]);
            re[k] = __int_as_float(dpp_masked<0x4E, 0xF, 0xA>(r, r));
            im[k] = __int_as_float(dpp_masked<0x4E, 0xF, 0xA>(i, i));
        }
    } else {
        // BC==1, BT==0: quad_perm [0,1,3,2] = 0xB4
#pragma unroll
        for (int k = 0; k < 8; ++k) {
            re[k] = __int_as_float(dpp_full<0xB4>(__float_as_int(re[k])));
            im[k] = __int_as_float(dpp_full<0xB4>(__float_as_int(im[k])));
        }
    }
}

// ---------- prep: cos/sin of 48 shared params into ws ----------

__global__ void qa_prep(const float* __restrict__ params, float* __restrict__ gc, int n) {
    int t = blockIdx.x * blockDim.x + threadIdx.x;
    if (t < n) {
        float th = params[t] * 0.5f;
        gc[2 * t]     = cosf(th);
        gc[2 * t + 1] = sinf(th);
    }
}

// ---------- main: TWO batch elements per wave ----------

__global__ __launch_bounds__(256, 4) void qa_sim(
    const float* __restrict__ x, const float* __restrict__ gc,
    float* __restrict__ out, int batch)
{
    int wid  = blockIdx.x * 4 + (threadIdx.x >> 6);
    int lane = threadIdx.x & 63;
    int b0 = wid * 2;
    if (b0 >= batch) return;
    int b1 = b0 + 1;
    int b1c = (b1 < batch) ? b1 : b0;

    bool px = probe32(lane);

    // ---- bulk-hoist all 96 shared cos/sin values (uniform -> scalar loads) ----
    float g[96];
#pragma unroll
    for (int i = 0; i < 96; ++i) g[i] = gc[i];

    // ---- closed-form product-state encoding, per element ----
    float re[8], im[8];
    int pcl = __popc((u32)lane);
    const int kpc[4] = { 0, 1, 1, 2 };
#pragma unroll
    for (int e = 0; e < 2; ++e) {
        const float* xb = x + (e ? b1c : b0) * 8;
        float4 xlo = *(const float4*)xb;
        float4 xhi = *(const float4*)(xb + 4);
        float c_[8], s_[8];
        __sincosf(xlo.x * 0.5f, &s_[0], &c_[0]);
        __sincosf(xlo.y * 0.5f, &s_[1], &c_[1]);
        __sincosf(xlo.z * 0.5f, &s_[2], &c_[2]);
        __sincosf(xlo.w * 0.5f, &s_[3], &c_[3]);
        __sincosf(xhi.x * 0.5f, &s_[4], &c_[4]);
        __sincosf(xhi.y * 0.5f, &s_[5], &c_[5]);
        __sincosf(xhi.z * 0.5f, &s_[6], &c_[6]);
        __sincosf(xhi.w * 0.5f, &s_[7], &c_[7]);

        float m6;
        m6  = ((lane >> 5) & 1) ? s_[2] : c_[2];
        m6 *= ((lane >> 4) & 1) ? s_[3] : c_[3];
        m6 *= ((lane >> 3) & 1) ? s_[4] : c_[4];
        m6 *= ((lane >> 2) & 1) ? s_[5] : c_[5];
        m6 *= ((lane >> 1) & 1) ? s_[6] : c_[6];
        m6 *= ( lane       & 1) ? s_[7] : c_[7];
        float kf[4] = { c_[0] * c_[1], c_[0] * s_[1], s_[0] * c_[1], s_[0] * s_[1] };
#pragma unroll
        for (int k = 0; k < 4; ++k) {
            float mk = m6 * kf[k];
            int p = pcl + kpc[k];
            float sgn = (p & 2) ? -mk : mk;
            re[e * 4 + k] = (p & 1) ? 0.f : sgn;
            im[e * 4 + k] = (p & 1) ? -sgn : 0.f;
        }
    }

    // ---- variational layers ----
#define VQ(l, i) { const int j = (l) * 24 + (i) * 3;                       \
                   apply_ry<7 - (i)>(re, im, lane, px, g[2*j],   g[2*j+1]);   \
                   apply_rz<7 - (i)>(re, im, lane,     g[2*j+2], g[2*j+3]); }
#define CN(i)    apply_cnot<7 - (i), 6 - (i)>(re, im, lane, px);
#define RXQ(l,i) { const int j = (l) * 24 + (i) * 3 + 2;                   \
                   apply_rx<7 - (i)>(re, im, lane, px, g[2*j], g[2*j+1]); }
#define LAYER(l) \
    VQ(l,0) CN(0) VQ(l,1) CN(1) VQ(l,2) CN(2) VQ(l,3) CN(3) \
    VQ(l,4) CN(4) VQ(l,5) CN(5) VQ(l,6) CN(6) VQ(l,7)       \
    RXQ(l,0) RXQ(l,1) RXQ(l,2) RXQ(l,3) RXQ(l,4) RXQ(l,5) RXQ(l,6) RXQ(l,7)

    LAYER(0)
    LAYER(1)
#undef LAYER
#undef RXQ
#undef CN
#undef VQ

    // ---- <Z_i> readout, both elements ----
    float p0a = fmaf(re[0], re[0], im[0] * im[0]);
    float p1a = fmaf(re[1], re[1], im[1] * im[1]);
    float p2a = fmaf(re[2], re[2], im[2] * im[2]);
    float p3a = fmaf(re[3], re[3], im[3] * im[3]);
    float p0b = fmaf(re[4], re[4], im[4] * im[4]);
    float p1b = fmaf(re[5], re[5], im[5] * im[5]);
    float p2b = fmaf(re[6], re[6], im[6] * im[6]);
    float p3b = fmaf(re[7], re[7], im[7] * im[7]);

    float z0a = (p0a + p1a) - (p2a + p3a), z0b = (p0b + p1b) - (p2b + p3b);
    float z1a = (p0a - p1a) + (p2a - p3a), z1b = (p0b - p1b) + (p2b - p3b);
    float Aa  = (p0a + p1a) + (p2a + p3a), Ab  = (p0b + p1b) + (p2b + p3b);

#define RED2(B) { z0a += lshfl<B>(z0a, px); z1a += lshfl<B>(z1a, px); \
                  z0b += lshfl<B>(z0b, px); z1b += lshfl<B>(z1b, px); }
    RED2(0) RED2(1) RED2(2) RED2(3) RED2(4) RED2(5)
#undef RED2

    // pruned Walsh-Hadamard on A (both elements interleaved)
    float Sa = Aa, Sb = Ab, Pa, Pb;
    float D0a, D1a, D2a, D3a, D4a, D5a, D0b, D1b, D2b, D3b, D4b, D5b;
#define WH(B, Da, Db) { Pa = lshfl<B>(Sa, px); Pb = lshfl<B>(Sb, px); \
                        Da = Sa - Pa; Db = Sb - Pb; Sa += Pa; Sb += Pb; }
    WH(0, D0a, D0b) WH(1, D1a, D1b) WH(2, D2a, D2b)
    WH(3, D3a, D3b) WH(4, D4a, D4b)
    Pa = lshfl<5>(Sa, px); Pb = lshfl<5>(Sb, px); D5a = Sa - Pa; D5b = Sb - Pb;
#undef WH

#define FIN(B, v) v += lshfl<B>(v, px);
    FIN(1, D0a) FIN(2, D0a) FIN(3, D0a) FIN(4, D0a) FIN(5, D0a)
    FIN(1, D0b) FIN(2, D0b) FIN(3, D0b) FIN(4, D0b) FIN(5, D0b)
    FIN(2, D1a) FIN(3, D1a) FIN(4, D1a) FIN(5, D1a)
    FIN(2, D1b) FIN(3, D1b) FIN(4, D1b) FIN(5, D1b)
    FIN(3, D2a) FIN(4, D2a) FIN(5, D2a)
    FIN(3, D2b) FIN(4, D2b) FIN(5, D2b)
    FIN(4, D3a) FIN(5, D3a)
    FIN(4, D3b) FIN(5, D3b)
    FIN(5, D4a)
    FIN(5, D4b)
#undef FIN

    if (lane == 0) {
        float4* o0 = (float4*)(out + b0 * 8);
        o0[0] = make_float4(z0a, z1a, D5a, D4a);
        o0[1] = make_float4(D3a, D2a, D1a, D0a);
        if (b1 < batch) {
            float4* o1 = (float4*)(out + b1 * 8);
            o1[0] = make_float4(z0b, z1b, D5b, D4b);
            o1[1] = make_float4(D3b, D2b, D1b, D0b);
        }
    }
}

extern "C" void kernel_launch(void* const* d_in, const int* in_sizes, int n_in,
                              void* d_out, int out_size, void* d_ws, size_t ws_size,
                              hipStream_t stream) {
    const float* x      = (const float*)d_in[0];   // (BATCH, 8)
    const float* params = (const float*)d_in[1];   // (2, 8, 3) = 48
    float* out = (float*)d_out;
    float* gc  = (float*)d_ws;                     // 96 floats of (cos,sin)

    int batch   = in_sizes[0] / 8;
    int nparams = in_sizes[1];                     // 48

    qa_prep<<<1, 64, 0, stream>>>(params, gc, nparams);

    // 2 elements per wave, 4 waves per block
    int nwaves = (batch + 1) / 2;
    int blocks = (nwaves + 3) / 4;
    qa_sim<<<blocks, 256, 0, stream>>>(x, gc, out, batch);
}

// Round 10
// 27.254 us; speedup vs baseline: 1.2097x; 1.0723x over previous
//
#include <hip/hip_runtime.h>

#define DEV __device__ __forceinline__

typedef unsigned u32;
typedef u32 u32x2 __attribute__((ext_vector_type(2)));
typedef _Float16 f16;
typedef f16   f16x8 __attribute__((ext_vector_type(8)));
typedef float f32x4 __attribute__((ext_vector_type(4)));

// ---------- DPP helpers ----------
template<int CTRL>
DEV int dpp_full(int src) {
    return __builtin_amdgcn_update_dpp(src, src, CTRL, 0xF, 0xF, false);
}
template<int CTRL, int RM, int BM>
DEV int dpp_masked(int old, int src) {
    return __builtin_amdgcn_update_dpp(old, src, CTRL, RM, BM, false);
}

// ---------- cross-lane xor-shuffle (r7-proven mix) ----------
template<int B>
DEV float lshfl(float x, bool px) {
    int xi = __float_as_int(x);
    if constexpr (B == 0) {
        return __int_as_float(dpp_full<0xB1>(xi));          // xor1
    } else if constexpr (B == 1) {
        return __int_as_float(dpp_full<0x4E>(xi));          // xor2
    } else if constexpr (B == 2) {
        return __int_as_float(__builtin_amdgcn_ds_swizzle(xi, 0x101F)); // xor4
    } else if constexpr (B == 3) {
        return __int_as_float(dpp_full<0x128>(xi));         // xor8
    } else if constexpr (B == 4) {
        return __int_as_float(__builtin_amdgcn_ds_swizzle(xi, 0x401F)); // xor16
    } else {
        u32x2 r = __builtin_amdgcn_permlane32_swap((u32)xi, (u32)xi, false, false);
        return __int_as_float((int)(px ? r.x : r.y));
    }
}

DEV bool probe32(int lane) {
    u32 p = (u32)((lane >> 5) & 1);
    u32x2 r = __builtin_amdgcn_permlane32_swap(p, p, false, false);
    return r.x == (p ^ 1u);
}

// ---------- complex pair primitives (fp32) ----------
DEV void rx_pair(float& r0, float& i0, float& r1, float& i1, float c, float s) {
    float nr0 = fmaf(c, r0,  s * i1);
    float ni0 = fmaf(c, i0, -s * r1);
    float nr1 = fmaf(c, r1,  s * i0);
    float ni1 = fmaf(c, i1, -s * r0);
    r0 = nr0; i0 = ni0; r1 = nr1; i1 = ni1;
}
DEV void ry_pair(float& r0, float& i0, float& r1, float& i1, float c, float s) {
    float nr0 = fmaf(c, r0, -s * r1);
    float ni0 = fmaf(c, i0, -s * i1);
    float nr1 = fmaf(c, r1,  s * r0);
    float ni1 = fmaf(c, i1,  s * i0);
    r0 = nr0; i0 = ni0; r1 = nr1; i1 = ni1;
}
DEV void rz_amp(float& r, float& i, float c, float ss) {
    float nr = fmaf(c, r, -ss * i);
    float ni = fmaf(c, i,  ss * r);
    r = nr; i = ni;
}

// ---------- gates on flat-index bit B (B = 7 - qubit), r7-verified ----------
template<int B>
DEV void apply_rx(float (&re)[4], float (&im)[4], int lane, bool px, float c, float s) {
    if constexpr (B == 7) {
        rx_pair(re[0], im[0], re[2], im[2], c, s);
        rx_pair(re[1], im[1], re[3], im[3], c, s);
    } else if constexpr (B == 6) {
        rx_pair(re[0], im[0], re[1], im[1], c, s);
        rx_pair(re[2], im[2], re[3], im[3], c, s);
    } else {
#pragma unroll
        for (int k = 0; k < 4; ++k) {
            float pr = lshfl<B>(re[k], px);
            float pi = lshfl<B>(im[k], px);
            re[k] = fmaf(c, re[k],  s * pi);
            im[k] = fmaf(c, im[k], -s * pr);
        }
    }
}
template<int B>
DEV void apply_ry(float (&re)[4], float (&im)[4], int lane, bool px, float c, float s) {
    if constexpr (B == 7) {
        ry_pair(re[0], im[0], re[2], im[2], c, s);
        ry_pair(re[1], im[1], re[3], im[3], c, s);
    } else if constexpr (B == 6) {
        ry_pair(re[0], im[0], re[1], im[1], c, s);
        ry_pair(re[2], im[2], re[3], im[3], c, s);
    } else {
        float ssel = ((lane >> B) & 1) ? s : -s;
#pragma unroll
        for (int k = 0; k < 4; ++k) {
            float pr = lshfl<B>(re[k], px);
            float pi = lshfl<B>(im[k], px);
            re[k] = fmaf(c, re[k], ssel * pr);
            im[k] = fmaf(c, im[k], ssel * pi);
        }
    }
}
template<int B>
DEV void apply_rz(float (&re)[4], float (&im)[4], int lane, float c, float s) {
    if constexpr (B == 7) {
        rz_amp(re[0], im[0], c, -s); rz_amp(re[1], im[1], c, -s);
        rz_amp(re[2], im[2], c,  s); rz_amp(re[3], im[3], c,  s);
    } else if constexpr (B == 6) {
        rz_amp(re[0], im[0], c, -s); rz_amp(re[1], im[1], c,  s);
        rz_amp(re[2], im[2], c, -s); rz_amp(re[3], im[3], c,  s);
    } else {
        float ss = ((lane >> B) & 1) ? s : -s;
#pragma unroll
        for (int k = 0; k < 4; ++k) rz_amp(re[k], im[k], c, ss);
    }
}
template<int BC, int BT>
DEV void apply_cnot(float (&re)[4], float (&im)[4], int lane, bool px) {
    if constexpr (BC == 7 && BT == 6) {
        float tr = re[2], ti = im[2];
        re[2] = re[3]; im[2] = im[3];
        re[3] = tr;    im[3] = ti;
    } else if constexpr (BC == 6) {
        re[1] = lshfl<5>(re[1], px); im[1] = lshfl<5>(im[1], px);
        re[3] = lshfl<5>(re[3], px); im[3] = lshfl<5>(im[3], px);
    } else if constexpr (BC == 5 && BT == 4) {
        bool ctrl = (lane >> 5) & 1;
#pragma unroll
        for (int k = 0; k < 4; ++k) {
            float pr = lshfl<4>(re[k], px);
            float pi = lshfl<4>(im[k], px);
            re[k] = ctrl ? pr : re[k];
            im[k] = ctrl ? pi : im[k];
        }
    } else if constexpr (BC == 4 && BT == 3) {
#pragma unroll
        for (int k = 0; k < 4; ++k) {
            int r = __float_as_int(re[k]), i = __float_as_int(im[k]);
            re[k] = __int_as_float(dpp_masked<0x128, 0xA, 0xF>(r, r));
            im[k] = __int_as_float(dpp_masked<0x128, 0xA, 0xF>(i, i));
        }
    } else if constexpr (BC == 3 && BT == 2) {
#pragma unroll
        for (int k = 0; k < 4; ++k) {
            int r = __float_as_int(re[k]), i = __float_as_int(im[k]);
            int tr = dpp_full<0x1B>(r), ti = dpp_full<0x1B>(i);
            re[k] = __int_as_float(dpp_masked<0x141, 0xF, 0xC>(r, tr));
            im[k] = __int_as_float(dpp_masked<0x141, 0xF, 0xC>(i, ti));
        }
    } else if constexpr (BC == 2 && BT == 1) {
#pragma unroll
        for (int k = 0; k < 4; ++k) {
            int r = __float_as_int(re[k]), i = __float_as_int(im[k]);
            re[k] = __int_as_float(dpp_masked<0x4E, 0xF, 0xA>(r, r));
            im[k] = __int_as_float(dpp_masked<0x4E, 0xF, 0xA>(i, i));
        }
    } else {
#pragma unroll
        for (int k = 0; k < 4; ++k) {
            re[k] = __int_as_float(dpp_full<0xB4>(__float_as_int(re[k])));
            im[k] = __int_as_float(dpp_full<0xB4>(__float_as_int(im[k])));
        }
    }
}

// ---------- kernel 1: build U (variational part) as packed MFMA B-operand ----------
// Wave j simulates circuit(e_j); Bmat[j][idx] = amp_idx. Packed layout:
// half_index = (kb*256 + idx)*32 + (j&31), kb = j>>5  -> one f16x8 per
// (idx, k-group) is exactly an MFMA B-fragment register block.

__global__ __launch_bounds__(256) void qa_genU(
    const float* __restrict__ params, f16* __restrict__ Bre, f16* __restrict__ Bim)
{
    int j    = blockIdx.x * 4 + (threadIdx.x >> 6);   // 0..255
    int lane = threadIdx.x & 63;
    bool px  = probe32(lane);

    // all 48 (cos,sin) computed per-lane (uniform inputs -> uniform values)
    float g[96];
#pragma unroll
    for (int t = 0; t < 48; ++t) {
        float th = params[t] * 0.5f;
        g[2 * t]     = __cosf(th);
        g[2 * t + 1] = __sinf(th);
    }

    // basis state e_j
    float re[4], im[4];
#pragma unroll
    for (int k = 0; k < 4; ++k) {
        re[k] = ((j >> 6) == k && (j & 63) == lane) ? 1.f : 0.f;
        im[k] = 0.f;
    }

#define VQ(l, i) { const int jj = (l) * 24 + (i) * 3;                      \
                   apply_ry<7 - (i)>(re, im, lane, px, g[2*jj],   g[2*jj+1]); \
                   apply_rz<7 - (i)>(re, im, lane,     g[2*jj+2], g[2*jj+3]); }
#define CN(i)    apply_cnot<7 - (i), 6 - (i)>(re, im, lane, px);
#define RXQ(l,i) { const int jj = (l) * 24 + (i) * 3 + 2;                  \
                   apply_rx<7 - (i)>(re, im, lane, px, g[2*jj], g[2*jj+1]); }
#define LAYER(l) \
    VQ(l,0) CN(0) VQ(l,1) CN(1) VQ(l,2) CN(2) VQ(l,3) CN(3) \
    VQ(l,4) CN(4) VQ(l,5) CN(5) VQ(l,6) CN(6) VQ(l,7)       \
    RXQ(l,0) RXQ(l,1) RXQ(l,2) RXQ(l,3) RXQ(l,4) RXQ(l,5) RXQ(l,6) RXQ(l,7)

    LAYER(0)
    LAYER(1)
#undef LAYER
#undef RXQ
#undef CN
#undef VQ

    int kb = j >> 5, jj = j & 31;
#pragma unroll
    for (int k = 0; k < 4; ++k) {
        int idx = k * 64 + lane;
        int o = (kb * 256 + idx) * 32 + jj;
        Bre[o] = (f16)re[k];
        Bim[o] = (f16)im[k];
    }
}

// ---------- kernel 2: encode + GEMM + Walsh readout ----------
// Block: 512 thr = 8 waves; 32 batch rows; wave (rg,cg) computes rows
// rg*16..+16 x cols cg*64..+64. C[b][idx] = sum_j S[b][j]*Bmat[j][idx].

__global__ __launch_bounds__(512, 2) void qa_gemm(
    const float* __restrict__ x,
    const f16* __restrict__ Bre, const f16* __restrict__ Bim,
    float* __restrict__ out, int batch)
{
    __shared__ __align__(16) f16 Ar[32 * 256];
    __shared__ __align__(16) f16 Ai[32 * 256];
    __shared__ float zb[4][32][8];

    int tid  = threadIdx.x;
    int w    = tid >> 6, lane = tid & 63;
    int rg   = w >> 2,   cg   = w & 3;
    int b0   = blockIdx.x * 32;
    if (b0 >= batch) return;

    // ---- encode rows w*4 .. w*4+3 into swizzled A LDS (fp16) ----
    int pcl = __popc((u32)lane);
    const int kpc[4] = { 0, 1, 1, 2 };
#pragma unroll
    for (int e = 0; e < 4; ++e) {
        int rl = w * 4 + e;
        const float* xb = x + (b0 + rl) * 8;
        float4 xlo = *(const float4*)xb;
        float4 xhi = *(const float4*)(xb + 4);
        float c_[8], s_[8];
        __sincosf(xlo.x * 0.5f, &s_[0], &c_[0]);
        __sincosf(xlo.y * 0.5f, &s_[1], &c_[1]);
        __sincosf(xlo.z * 0.5f, &s_[2], &c_[2]);
        __sincosf(xlo.w * 0.5f, &s_[3], &c_[3]);
        __sincosf(xhi.x * 0.5f, &s_[4], &c_[4]);
        __sincosf(xhi.y * 0.5f, &s_[5], &c_[5]);
        __sincosf(xhi.z * 0.5f, &s_[6], &c_[6]);
        __sincosf(xhi.w * 0.5f, &s_[7], &c_[7]);

        float m6;
        m6  = ((lane >> 5) & 1) ? s_[2] : c_[2];
        m6 *= ((lane >> 4) & 1) ? s_[3] : c_[3];
        m6 *= ((lane >> 3) & 1) ? s_[4] : c_[4];
        m6 *= ((lane >> 2) & 1) ? s_[5] : c_[5];
        m6 *= ((lane >> 1) & 1) ? s_[6] : c_[6];
        m6 *= ( lane       & 1) ? s_[7] : c_[7];
        float kf[4] = { c_[0] * c_[1], c_[0] * s_[1], s_[0] * c_[1], s_[0] * s_[1] };
        int sw = (rl & 7) << 3;
#pragma unroll
        for (int k = 0; k < 4; ++k) {
            float mk = m6 * kf[k];
            int p = pcl + kpc[k];
            float sgn = (p & 2) ? -mk : mk;
            float vre = (p & 1) ? 0.f : sgn;
            float vim = (p & 1) ? -sgn : 0.f;
            int j  = k * 64 + lane;
            int hi = rl * 256 + (j ^ sw);
            Ar[hi] = (f16)vre;
            Ai[hi] = (f16)vim;
        }
    }
    __syncthreads();

    // ---- K loop: 8 steps of 32, 16 MFMAs each ----
    f32x4 accre[4], accim[4];
#pragma unroll
    for (int t = 0; t < 4; ++t) { accre[t] = (f32x4)0.f; accim[t] = (f32x4)0.f; }

    int colbase = cg * 64 + (lane & 15);
    int arow    = rg * 16 + (lane & 15);   // A-operand row (lane&15 mapping)
    int kg      = lane >> 4;
    const f16x8* B8re = reinterpret_cast<const f16x8*>(Bre);
    const f16x8* B8im = reinterpret_cast<const f16x8*>(Bim);

#pragma unroll
    for (int kb = 0; kb < 8; ++kb) {
        int afi = arow * 32 + ((kb * 4 + kg) ^ (arow & 7));
        f16x8 are = *reinterpret_cast<const f16x8*>(&Ar[afi * 8]);
        f16x8 aim = *reinterpret_cast<const f16x8*>(&Ai[afi * 8]);
        f16x8 ain;
#pragma unroll
        for (int i = 0; i < 8; ++i) ain[i] = -aim[i];
#pragma unroll
        for (int t = 0; t < 4; ++t) {
            int idx = colbase + t * 16;
            int bo  = (kb * 256 + idx) * 4 + kg;
            f16x8 bre = B8re[bo];
            f16x8 bim = B8im[bo];
            accre[t] = __builtin_amdgcn_mfma_f32_16x16x32_f16(are, bre, accre[t], 0, 0, 0);
            accre[t] = __builtin_amdgcn_mfma_f32_16x16x32_f16(ain, bim, accre[t], 0, 0, 0);
            accim[t] = __builtin_amdgcn_mfma_f32_16x16x32_f16(are, bim, accim[t], 0, 0, 0);
            accim[t] = __builtin_amdgcn_mfma_f32_16x16x32_f16(aim, bre, accim[t], 0, 0, 0);
        }
    }

    // ---- Walsh epilogue: Z_q = sum_idx (1-2*bit_{7-q}(idx)) * |c|^2 ----
    float z[4][8];
#pragma unroll
    for (int r = 0; r < 4; ++r)
#pragma unroll
        for (int q = 0; q < 8; ++q) z[r][q] = 0.f;

#pragma unroll
    for (int t = 0; t < 4; ++t) {
        int idx = colbase + t * 16;
#pragma unroll
        for (int r = 0; r < 4; ++r) {
            float cr = accre[t][r], ci = accim[t][r];
            float p = fmaf(cr, cr, ci * ci);
#pragma unroll
            for (int q = 0; q < 8; ++q)
                z[r][q] += ((idx >> (7 - q)) & 1) ? -p : p;
        }
    }

    // reduce over the 16 column-lanes (lane bits 0..3)
#pragma unroll
    for (int r = 0; r < 4; ++r)
#pragma unroll
        for (int q = 0; q < 8; ++q) {
            z[r][q] += lshfl<0>(z[r][q], false);
            z[r][q] += lshfl<1>(z[r][q], false);
            z[r][q] += lshfl<2>(z[r][q], false);
            z[r][q] += lshfl<3>(z[r][q], false);
        }

    // D-layout rows: row = rg*16 + (lane>>4)*4 + r
    if ((lane & 15) < 8) {
        int q = lane & 7;
#pragma unroll
        for (int r = 0; r < 4; ++r)
            zb[cg][rg * 16 + (lane >> 4) * 4 + r][q] = z[r][q];
    }
    __syncthreads();

    if (tid < 256) {
        int row = tid >> 3, q = tid & 7;
        float v = zb[0][row][q] + zb[1][row][q] + zb[2][row][q] + zb[3][row][q];
        out[(b0 + row) * 8 + q] = v;
    }
}

extern "C" void kernel_launch(void* const* d_in, const int* in_sizes, int n_in,
                              void* d_out, int out_size, void* d_ws, size_t ws_size,
                              hipStream_t stream) {
    const float* x      = (const float*)d_in[0];   // (BATCH, 8)
    const float* params = (const float*)d_in[1];   // (2, 8, 3) = 48
    float* out = (float*)d_out;

    f16* Bre = (f16*)d_ws;              // 256x256 packed halves = 128 KB
    f16* Bim = Bre + 65536;             // next 128 KB

    int batch = in_sizes[0] / 8;

    qa_genU<<<64, 256, 0, stream>>>(params, Bre, Bim);

    int blocks = (batch + 31) / 32;
    qa_gemm<<<blocks, 512, 0, stream>>>(x, Bre, Bim, out, batch);
}